// Round 15
// baseline (2282.560 us; speedup 1.0000x reference)
//
#include <hip/hip_runtime.h>
#include <stdint.h>

#define TN 1024
#define CD 192
#define NB 8
#define NCLUST 196
#define NMERGE (TN - NCLUST)
#define TAILN 168              // handoff threshold (168^2 floats fit in LDS)
#define PCAP 64                // tail: max pairs per round
#define HIMASK 0xFFFFFFFF00000000ull

typedef unsigned long long ull;

__device__ __forceinline__ uint32_t f2sort(float f) {
    uint32_t u = __float_as_uint(f);
    return u ^ ((u >> 31) ? 0xFFFFFFFFu : 0x80000000u);
}

template<int CTRL>
__device__ __forceinline__ ull dpp_min64(ull x) {
    int lo = (int)(uint32_t)x, hi = (int)(uint32_t)(x >> 32);
    int tlo = __builtin_amdgcn_update_dpp(lo, lo, CTRL, 0xF, 0xF, false);
    int thi = __builtin_amdgcn_update_dpp(hi, hi, CTRL, 0xF, 0xF, false);
    ull t = ((ull)(uint32_t)thi << 32) | (uint32_t)tlo;
    return (t < x) ? t : x;
}
__device__ __forceinline__ ull wmin64_all(ull x) {
    x = dpp_min64<0x111>(x); x = dpp_min64<0x112>(x);
    x = dpp_min64<0x114>(x); x = dpp_min64<0x118>(x);
    x = dpp_min64<0x142>(x); x = dpp_min64<0x143>(x);
    int lo = __builtin_amdgcn_readlane((int)(uint32_t)x, 63);
    int hi = __builtin_amdgcn_readlane((int)(uint32_t)(x >> 32), 63);
    return ((ull)(uint32_t)hi << 32) | (uint32_t)lo;
}

// ---------------- normalize rows: xn = x / ||x|| ----------------
__global__ void norm_kernel(const float* __restrict__ x, float* __restrict__ xn) {
    int row = blockIdx.x;
    int t = threadIdx.x;
    __shared__ float ssum[4];
    float v = 0.f;
    if (t < CD) v = x[(size_t)row * CD + t];
    float s = v * v;
    #pragma unroll
    for (int off = 32; off > 0; off >>= 1) s += __shfl_xor(s, off, 64);
    if ((t & 63) == 0) ssum[t >> 6] = s;
    __syncthreads();
    float tot = ssum[0] + ssum[1] + ssum[2] + ssum[3];
    float nrm = __fsqrt_rn(tot);
    if (t < CD) xn[(size_t)row * CD + t] = __fdiv_rn(v, nrm);
}

// ---------------- dist = 1 - xn @ xn^T, 64x64 tiles ----------------
#define KC 32
__global__ __launch_bounds__(256) void dist_kernel(const float* __restrict__ xn,
                                                   float* __restrict__ dout) {
    int b = blockIdx.z;
    int bm = blockIdx.y, bn = blockIdx.x;
    const float* X = xn + (size_t)b * TN * CD;
    __shared__ float As[KC][68];
    __shared__ float Bs[KC][68];
    int tid = threadIdx.x;
    int tx = tid & 15, ty = tid >> 4;
    int lr = tid >> 2;
    int lq = tid & 3;
    float acc[4][4];
    #pragma unroll
    for (int r = 0; r < 4; ++r)
        #pragma unroll
        for (int c = 0; c < 4; ++c) acc[r][c] = 0.f;

    for (int kc = 0; kc < CD; kc += KC) {
        float4 a0 = *(const float4*)&X[(size_t)(bm * 64 + lr) * CD + kc + lq * 4];
        float4 a1 = *(const float4*)&X[(size_t)(bm * 64 + lr) * CD + kc + (lq + 4) * 4];
        float4 b0 = *(const float4*)&X[(size_t)(bn * 64 + lr) * CD + kc + lq * 4];
        float4 b1 = *(const float4*)&X[(size_t)(bn * 64 + lr) * CD + kc + (lq + 4) * 4];
        __syncthreads();
        As[lq * 4 + 0][lr] = a0.x; As[lq * 4 + 1][lr] = a0.y;
        As[lq * 4 + 2][lr] = a0.z; As[lq * 4 + 3][lr] = a0.w;
        As[lq * 4 + 16][lr] = a1.x; As[lq * 4 + 17][lr] = a1.y;
        As[lq * 4 + 18][lr] = a1.z; As[lq * 4 + 19][lr] = a1.w;
        Bs[lq * 4 + 0][lr] = b0.x; Bs[lq * 4 + 1][lr] = b0.y;
        Bs[lq * 4 + 2][lr] = b0.z; Bs[lq * 4 + 3][lr] = b0.w;
        Bs[lq * 4 + 16][lr] = b1.x; Bs[lq * 4 + 17][lr] = b1.y;
        Bs[lq * 4 + 18][lr] = b1.z; Bs[lq * 4 + 19][lr] = b1.w;
        __syncthreads();
        #pragma unroll
        for (int kk = 0; kk < KC; ++kk) {
            float4 av = *(const float4*)&As[kk][ty * 4];
            float4 bv = *(const float4*)&Bs[kk][tx * 4];
            acc[0][0] += av.x * bv.x; acc[0][1] += av.x * bv.y;
            acc[0][2] += av.x * bv.z; acc[0][3] += av.x * bv.w;
            acc[1][0] += av.y * bv.x; acc[1][1] += av.y * bv.y;
            acc[1][2] += av.y * bv.z; acc[1][3] += av.y * bv.w;
            acc[2][0] += av.z * bv.x; acc[2][1] += av.z * bv.y;
            acc[2][2] += av.z * bv.z; acc[2][3] += av.z * bv.w;
            acc[3][0] += av.w * bv.x; acc[3][1] += av.w * bv.y;
            acc[3][2] += av.w * bv.z; acc[3][3] += av.w * bv.w;
        }
    }
    size_t obase = (size_t)b * TN * TN;
    #pragma unroll
    for (int r = 0; r < 4; ++r) {
        int mrow = bm * 64 + ty * 4 + r;
        float4 o;
        o.x = 1.0f - acc[r][0]; o.y = 1.0f - acc[r][1];
        o.z = 1.0f - acc[r][2]; o.w = 1.0f - acc[r][3];
        size_t idx = obase + (size_t)mrow * TN + bn * 64 + tx * 4;
        *(float4*)&dout[idx] = o;
    }
}

// ---------------- head: 1 WG per batch, ping-pong rewrite rounds while N > TAILN ----------------
// Same round math as R13/R14 (mutual-NN pairs, rank-sorted by (val,gid_i,gid_j); rewrite
// cur(N)->nxt(Nn) with inline LW / two-level cross formulas; fused NN). Single WG per batch
// => no grid syncs; same-CU global RAW is coherent after __syncthreads (validated R1-R10).
__global__ __launch_bounds__(1024)
void head_kernel(const float* __restrict__ Dinit,
                 float* __restrict__ DA, float* __restrict__ DB,
                 float* __restrict__ szg, int* __restrict__ gidg,
                 ull* __restrict__ mkg, int* __restrict__ metag) {
    int b = blockIdx.x;
    int k = threadIdx.x;
    int lane = k & 63, wv = k >> 6;

    __shared__ ull rk_s[TN];
    __shared__ float sz_s[TN];
    __shared__ int gid_s[TN];
    __shared__ int ts_s[TN];
    __shared__ int n2o_s[TN];
    __shared__ unsigned char dead_s[TN];
    __shared__ int pi_t[512], pj_t[512];
    __shared__ ull pk_t[512];
    __shared__ int spi_s[512], spj_s[512];
    __shared__ ull mk_s[TN];
    __shared__ int wcnt[16], woffp[16];
    __shared__ int npair_s;

    sz_s[k] = 1.0f;
    gid_s[k] = k;
    mk_s[k] = ~0ull;

    // init NN over Dinit
    const float* D0 = Dinit + (size_t)b * TN * TN;
    for (int r = wv; r < TN; r += 16) {
        const float* Rr = D0 + (size_t)r * TN;
        ull best = ~0ull;
        for (int s = lane; s < TN; s += 64)
            if (s != r) {
                ull key = ((ull)f2sort(Rr[s]) << 32) | (uint32_t)s;
                if (key < best) best = key;
            }
        best = wmin64_all(best);
        if (lane == 0) rk_s[r] = best;
    }
    __syncthreads();

    float* DAb = DA + (size_t)b * TN * TN;
    float* DBb = DB + (size_t)b * TN * TN;
    const float* cur = D0;
    float* nxt = DAb;
    int N = TN, nm = 0;

    while (N > TAILN) {
        // ---- plan (WG-local, deterministic) ----
        ts_s[k] = -1;
        dead_s[k] = 0;
        __syncthreads();
        bool mut = false; int cpart = 0;
        if (k < N) {
            ull K = rk_s[k];
            int c = (int)(uint32_t)K;
            if ((int)(uint32_t)rk_s[c] == k && k < c) { mut = true; cpart = c; }
        }
        ull bm = __ballot(mut);
        int lanepre = __popcll(bm & (((ull)1 << lane) - 1ull));
        if (lane == 0) wcnt[wv] = __popcll(bm);
        __syncthreads();
        if (k == 0) {
            int run = 0;
            #pragma unroll
            for (int u = 0; u < 16; ++u) { woffp[u] = run; run += wcnt[u]; }
            npair_s = run;
        }
        __syncthreads();
        if (mut) { int idx = woffp[wv] + lanepre; pi_t[idx] = k; pj_t[idx] = cpart; }
        __syncthreads();
        int np = npair_s;
        if (np == 0) {                       // defensive: force global-min pair
            ull cand = ~0ull;
            if (k < N) cand = (rk_s[k] & HIMASK) | (uint32_t)k;
            cand = wmin64_all(cand);
            if (lane == 0) pk_t[wv] = cand;
            __syncthreads();
            if (k == 0) {
                ull g = pk_t[0];
                for (int u = 1; u < 16; ++u) if (pk_t[u] < g) g = pk_t[u];
                int r = (int)(uint32_t)g;
                int c = (int)(uint32_t)rk_s[r];
                pi_t[0] = r < c ? r : c;
                pj_t[0] = r < c ? c : r;
                npair_s = 1;
            }
            __syncthreads();
            np = 1;
        }
        if (k < np) {
            int i = pi_t[k], j = pj_t[k];
            uint32_t vb = (uint32_t)(rk_s[i] >> 32);
            pk_t[k] = ((ull)vb << 20) | ((ull)(uint32_t)gid_s[i] << 10) | (ull)(uint32_t)gid_s[j];
        }
        __syncthreads();
        if (k < np) {                        // rank-sort (keys distinct: gid_j unique)
            ull mk = pk_t[k];
            int rank = 0;
            for (int u = 0; u < np; ++u) if (pk_t[u] < mk) ++rank;
            spi_s[rank] = pi_t[k]; spj_s[rank] = pj_t[k];
            mk_s[nm + rank] = mk;
        }
        __syncthreads();
        if (k < np) { ts_s[spi_s[k]] = k; dead_s[spj_s[k]] = 1; }
        __syncthreads();
        bool alive_ = (k < N) && !dead_s[k];
        ull am = __ballot(alive_);
        int apre = __popcll(am & (((ull)1 << lane) - 1ull));
        if (lane == 0) wcnt[wv] = __popcll(am);
        __syncthreads();
        if (k == 0) {
            int run = 0;
            #pragma unroll
            for (int u = 0; u < 16; ++u) { woffp[u] = run; run += wcnt[u]; }
        }
        __syncthreads();
        if (alive_) n2o_s[woffp[wv] + apre] = k;
        int Nn = N - np;
        __syncthreads();

        // ---- rewrite cur(N) -> nxt(Nn), fused NN -> rk_s ----
        for (int ap = wv; ap < Nn; ap += 16) {
            int a = n2o_s[ap];
            int qa = ts_s[a];
            float* drow = nxt + (size_t)ap * Nn;
            ull best = ~0ull;
            if (qa < 0) {
                const float* Ra = cur + (size_t)a * N;
                for (int bp = lane; bp < Nn; bp += 64) {
                    int bo = n2o_s[bp];
                    int qb = ts_s[bo];
                    float val;
                    if (qb < 0) val = Ra[bo];
                    else {
                        int iq = spi_s[qb], jq = spj_s[qb];
                        float niq = sz_s[iq], njq = sz_s[jq];
                        float sq = __fadd_rn(niq, njq);
                        val = __fdiv_rn(__fadd_rn(__fmul_rn(niq, Ra[iq]),
                                                  __fmul_rn(njq, Ra[jq])), sq);
                    }
                    drow[bp] = val;
                    if (bp != ap) {
                        ull key = ((ull)f2sort(val) << 32) | (uint32_t)bp;
                        if (key < best) best = key;
                    }
                }
            } else {
                int ii = spi_s[qa], jj = spj_s[qa];
                float ni = sz_s[ii], nj = sz_s[jj], ss = __fadd_rn(ni, nj);
                const float* Ri = cur + (size_t)ii * N;
                const float* Rj = cur + (size_t)jj * N;
                for (int bp = lane; bp < Nn; bp += 64) {
                    int bo = n2o_s[bp];
                    int qb = ts_s[bo];
                    float val;
                    if (qb < 0) {
                        val = __fdiv_rn(__fadd_rn(__fmul_rn(ni, Ri[bo]),
                                                  __fmul_rn(nj, Rj[bo])), ss);
                    } else if (qb == qa) {
                        val = 0.0f;          // diagonal, never read
                    } else {
                        int p = qa < qb ? qa : qb, q2 = qa < qb ? qb : qa;
                        int ip = spi_s[p], jp = spj_s[p], iq = spi_s[q2], jq = spj_s[q2];
                        float nip = sz_s[ip], njp = sz_s[jp], sp = __fadd_rn(nip, njp);
                        float niq = sz_s[iq], njq = sz_s[jq], sq = __fadd_rn(niq, njq);
                        float t1 = __fdiv_rn(__fadd_rn(__fmul_rn(nip, cur[(size_t)ip * N + iq]),
                                                       __fmul_rn(njp, cur[(size_t)jp * N + iq])), sp);
                        float t2 = __fdiv_rn(__fadd_rn(__fmul_rn(nip, cur[(size_t)ip * N + jq]),
                                                       __fmul_rn(njp, cur[(size_t)jp * N + jq])), sp);
                        val = __fdiv_rn(__fadd_rn(__fmul_rn(niq, t1), __fmul_rn(njq, t2)), sq);
                    }
                    drow[bp] = val;
                    if (bp != ap) {
                        ull key = ((ull)f2sort(val) << 32) | (uint32_t)bp;
                        if (key < best) best = key;
                    }
                }
            }
            best = wmin64_all(best);
            if (lane == 0) rk_s[ap] = best;
        }
        __syncthreads();
        // ---- compact sizes/gid ----
        float ns = 0.f; int ng = 0; bool act = (k < Nn);
        if (act) {
            int a = n2o_s[k]; int q = ts_s[a];
            ns = (q >= 0) ? __fadd_rn(sz_s[spi_s[q]], sz_s[spj_s[q]]) : sz_s[a];
            ng = gid_s[a];
        }
        __syncthreads();
        if (act) { sz_s[k] = ns; gid_s[k] = ng; }
        nm += np;
        N = Nn;
        __syncthreads();        // drains rewrite stores; next round's reads are coherent (same CU)
        cur = nxt;
        nxt = (nxt == DAb) ? DBb : DAb;
    }

    // ---- state dump for tail kernel ----
    if (k < N) { szg[b * TN + k] = sz_s[k]; gidg[b * TN + k] = gid_s[k]; }
    mkg[(size_t)b * TN + k] = mk_s[k];
    if (k == 0) {
        metag[b * 4 + 0] = N;
        metag[b * 4 + 1] = nm;
        metag[b * 4 + 2] = (cur == DAb) ? 1 : 2;
    }
}

// ---------------- Kernel B: LDS-resident tail + cut + labels (verbatim from R14) ----------------
__global__ __launch_bounds__(1024)
void tail_kernel(const float* __restrict__ DA, const float* __restrict__ DB,
                 const float* __restrict__ szg, const int* __restrict__ gidg,
                 const ull* __restrict__ mkg, const int* __restrict__ metag,
                 float* __restrict__ out_labels) {
    int b = blockIdx.x;
    int k = threadIdx.x;
    int lane = k & 63, wv = k >> 6;

    __shared__ float Dl[TAILN * TAILN];
    __shared__ ull rk_s[TAILN];
    __shared__ float sz_s[TAILN];
    __shared__ int gid_s[TAILN];
    __shared__ unsigned char alive[TAILN];
    __shared__ int tsl[TAILN];
    __shared__ float F[PCAP * PCAP];
    __shared__ int pi_t[96], pj_t[96];
    __shared__ ull pk_t[96];
    __shared__ int spi_s[PCAP], spj_s[PCAP];
    __shared__ ull mk_s[TN];
    __shared__ int par_s[TN];
    __shared__ uint32_t rw[32];
    __shared__ int woff2[32];
    __shared__ ull wpA[16];
    __shared__ int npair_s;

    int N = metag[b * 4 + 0];
    int nm = metag[b * 4 + 1];
    int which = metag[b * 4 + 2];
    const float* src = ((which == 1) ? DA : DB) + (size_t)b * TN * TN;

    for (int idx = k; idx < N * N; idx += 1024) Dl[idx] = src[idx];
    mk_s[k] = mkg[(size_t)b * TN + k];
    if (k < N) {
        sz_s[k] = szg[b * TN + k];
        gid_s[k] = gidg[b * TN + k];
        alive[k] = 1;
        tsl[k] = -1;
    }
    __syncthreads();

    int na = N;
    for (int round = 0; round < 600 && na > 1; ++round) {
        for (int r = wv; r < N; r += 16) {
            ull best = ~0ull;
            if (alive[r]) {
                for (int s = lane; s < N; s += 64)
                    if (alive[s] && s != r) {
                        ull key = ((ull)f2sort(Dl[r * N + s]) << 32) | (uint32_t)s;
                        if (key < best) best = key;
                    }
                best = wmin64_all(best);
            }
            if (lane == 0) rk_s[r] = best;
        }
        if (k == 0) npair_s = 0;
        __syncthreads();
        if (k < N && alive[k]) {
            ull K = rk_s[k];
            int c = (int)(uint32_t)K;
            if ((int)(uint32_t)rk_s[c] == k && k < c) {
                int idx = atomicAdd(&npair_s, 1);
                pi_t[idx] = k; pj_t[idx] = c;
            }
        }
        __syncthreads();
        int np = npair_s;
        if (np == 0) {
            ull cand = ~0ull;
            if (k < N && alive[k]) cand = (rk_s[k] & HIMASK) | (uint32_t)k;
            cand = wmin64_all(cand);
            if (lane == 0) wpA[wv] = cand;
            __syncthreads();
            if (k == 0) {
                ull g = wpA[0];
                for (int u = 1; u < 16; ++u) if (wpA[u] < g) g = wpA[u];
                int r = (int)(uint32_t)g;
                int c = (int)(uint32_t)rk_s[r];
                pi_t[0] = r < c ? r : c;
                pj_t[0] = r < c ? c : r;
                npair_s = 1;
            }
            __syncthreads();
            np = 1;
        }
        int P = np < PCAP ? np : PCAP;
        if (k < np) {
            int i = pi_t[k], j = pj_t[k];
            uint32_t vb = (uint32_t)(rk_s[i] >> 32);
            pk_t[k] = ((ull)vb << 20) | ((ull)(uint32_t)gid_s[i] << 10) | (ull)(uint32_t)gid_s[j];
        }
        __syncthreads();
        if (k < np) {
            ull mk = pk_t[k];
            int rank = 0;
            for (int u = 0; u < np; ++u) if (pk_t[u] < mk) ++rank;
            if (rank < P) { spi_s[rank] = pi_t[k]; spj_s[rank] = pj_t[k]; mk_s[nm + rank] = mk; }
        }
        __syncthreads();
        for (int t = k; t < P * P; t += 1024) {
            int p = t / P, q = t - p * P;
            if (p < q) {
                int ip = spi_s[p], jp = spj_s[p], iq = spi_s[q], jq = spj_s[q];
                float nip = sz_s[ip], njp = sz_s[jp], sp = __fadd_rn(nip, njp);
                float niq = sz_s[iq], njq = sz_s[jq], sq = __fadd_rn(niq, njq);
                float t1 = __fdiv_rn(__fadd_rn(__fmul_rn(nip, Dl[ip * N + iq]),
                                               __fmul_rn(njp, Dl[jp * N + iq])), sp);
                float t2 = __fdiv_rn(__fadd_rn(__fmul_rn(nip, Dl[ip * N + jq]),
                                               __fmul_rn(njp, Dl[jp * N + jq])), sp);
                F[p * PCAP + q] = __fdiv_rn(__fadd_rn(__fmul_rn(niq, t1), __fmul_rn(njq, t2)), sq);
            }
        }
        if (k < P) { tsl[spi_s[k]] = k; alive[spj_s[k]] = 0; }
        __syncthreads();
        for (int q = wv; q < P; q += 16) {
            int ii = spi_s[q], jj = spj_s[q];
            float ni = sz_s[ii], nj = sz_s[jj], ss = __fadd_rn(ni, nj);
            for (int s = lane; s < N; s += 64) {
                if (!alive[s] || s == ii) continue;
                int tp = tsl[s];
                float val;
                if (tp >= 0) {
                    int p2 = tp < q ? tp : q, q2 = tp < q ? q : tp;
                    val = F[p2 * PCAP + q2];
                } else {
                    val = __fdiv_rn(__fadd_rn(__fmul_rn(ni, Dl[ii * N + s]),
                                              __fmul_rn(nj, Dl[jj * N + s])), ss);
                }
                Dl[ii * N + s] = val;
                Dl[s * N + ii] = val;
            }
        }
        __syncthreads();
        if (k < P) {
            int ii = spi_s[k];
            sz_s[ii] = __fadd_rn(sz_s[ii], sz_s[spj_s[k]]);
            tsl[ii] = -1;
        }
        nm += P;
        na -= P;
        __syncthreads();
    }

    // epilogue: cut at 828 smallest merge keys, union-find, rank labels
    __syncthreads();
    par_s[k] = k;
    if (k < 32) rw[k] = 0;
    __syncthreads();
    if (k < TN - 1) {
        ull mk = mk_s[k];
        if (mk != ~0ull) {
            int rank = 0;
            for (int u = 0; u < TN - 1; ++u) if (mk_s[u] < mk) ++rank;
            if (rank < NMERGE) {
                int jj = (int)(mk & 1023ull);
                int ii = (int)((mk >> 10) & 1023ull);
                par_s[jj] = ii;
            }
        }
    }
    __syncthreads();
    #pragma unroll
    for (int it = 0; it < 11; ++it) {
        int p1 = par_s[k];
        int g = par_s[p1];
        __syncthreads();
        par_s[k] = g;
        __syncthreads();
    }
    if (par_s[k] == k) atomicOr(&rw[k >> 5], 1u << (k & 31));
    __syncthreads();
    if (k == 0) {
        int run = 0;
        for (int u = 0; u < 32; ++u) { woff2[u] = run; run += __popc(rw[u]); }
    }
    __syncthreads();
    int p = par_s[k];
    int rank = woff2[p >> 5] + __popc(rw[p >> 5] & ((1u << (p & 31)) - 1u));
    out_labels[(size_t)b * TN + k] = (float)rank;
}

extern "C" void kernel_launch(void* const* d_in, const int* in_sizes, int n_in,
                              void* d_out, int out_size, void* d_ws, size_t ws_size,
                              hipStream_t stream) {
    const float* x = (const float*)d_in[0];
    float* out = (float*)d_out;

    float* xn   = (float*)d_ws;                             // NB*TN*CD  (6.29 MB)
    float* DAp  = xn + (size_t)NB * TN * CD;                // NB*TN*TN  (33.6 MB)
    float* DBp  = DAp + (size_t)NB * TN * TN;               // NB*TN*TN  (33.6 MB)
    float* szg  = DBp + (size_t)NB * TN * TN;               // NB*TN f32
    int*   gidg = (int*)(szg + (size_t)NB * TN);            // NB*TN i32
    ull*   mkg  = (ull*)(gidg + (size_t)NB * TN);           // NB*TN u64
    int*   metag = (int*)(mkg + (size_t)NB * TN);           // NB*4 ints

    float* dist_out   = out;
    float* labels_out = out + (size_t)NB * TN * TN;

    norm_kernel<<<NB * TN, 256, 0, stream>>>(x, xn);
    dim3 g2(16, 16, NB);
    dist_kernel<<<g2, 256, 0, stream>>>(xn, dist_out);
    head_kernel<<<NB, 1024, 0, stream>>>(dist_out, DAp, DBp, szg, gidg, mkg, metag);
    tail_kernel<<<NB, 1024, 0, stream>>>(DAp, DBp, szg, gidg, mkg, metag, labels_out);
}

// Round 16
// 453.229 us; speedup vs baseline: 5.0362x; 5.0362x over previous
//
#include <hip/hip_runtime.h>
#include <stdint.h>

#define TN 1024
#define CD 192
#define NB 8
#define WPB 16
#define NWG (NB * WPB)
#define NCLUST 196
#define NMERGE (TN - NCLUST)
#define TAILN 168              // handoff threshold (168^2 floats fit in LDS)
#define PCAP 64                // tail: max pairs per round
#define NROUNDS 16             // fixed head-round dispatches (measured need ~7)
#define HIMASK 0xFFFFFFFF00000000ull

typedef unsigned long long ull;

__device__ __forceinline__ uint32_t f2sort(float f) {
    uint32_t u = __float_as_uint(f);
    return u ^ ((u >> 31) ? 0xFFFFFFFFu : 0x80000000u);
}

template<int CTRL>
__device__ __forceinline__ ull dpp_min64(ull x) {
    int lo = (int)(uint32_t)x, hi = (int)(uint32_t)(x >> 32);
    int tlo = __builtin_amdgcn_update_dpp(lo, lo, CTRL, 0xF, 0xF, false);
    int thi = __builtin_amdgcn_update_dpp(hi, hi, CTRL, 0xF, 0xF, false);
    ull t = ((ull)(uint32_t)thi << 32) | (uint32_t)tlo;
    return (t < x) ? t : x;
}
__device__ __forceinline__ ull wmin64_all(ull x) {
    x = dpp_min64<0x111>(x); x = dpp_min64<0x112>(x);
    x = dpp_min64<0x114>(x); x = dpp_min64<0x118>(x);
    x = dpp_min64<0x142>(x); x = dpp_min64<0x143>(x);
    int lo = __builtin_amdgcn_readlane((int)(uint32_t)x, 63);
    int hi = __builtin_amdgcn_readlane((int)(uint32_t)(x >> 32), 63);
    return ((ull)(uint32_t)hi << 32) | (uint32_t)lo;
}

// ---------------- normalize rows: xn = x / ||x|| ----------------
__global__ void norm_kernel(const float* __restrict__ x, float* __restrict__ xn) {
    int row = blockIdx.x;
    int t = threadIdx.x;
    __shared__ float ssum[4];
    float v = 0.f;
    if (t < CD) v = x[(size_t)row * CD + t];
    float s = v * v;
    #pragma unroll
    for (int off = 32; off > 0; off >>= 1) s += __shfl_xor(s, off, 64);
    if ((t & 63) == 0) ssum[t >> 6] = s;
    __syncthreads();
    float tot = ssum[0] + ssum[1] + ssum[2] + ssum[3];
    float nrm = __fsqrt_rn(tot);
    if (t < CD) xn[(size_t)row * CD + t] = __fdiv_rn(v, nrm);
}

// ---------------- dist = 1 - xn @ xn^T, 64x64 tiles ----------------
#define KC 32
__global__ __launch_bounds__(256) void dist_kernel(const float* __restrict__ xn,
                                                   float* __restrict__ dout) {
    int b = blockIdx.z;
    int bm = blockIdx.y, bn = blockIdx.x;
    const float* X = xn + (size_t)b * TN * CD;
    __shared__ float As[KC][68];
    __shared__ float Bs[KC][68];
    int tid = threadIdx.x;
    int tx = tid & 15, ty = tid >> 4;
    int lr = tid >> 2;
    int lq = tid & 3;
    float acc[4][4];
    #pragma unroll
    for (int r = 0; r < 4; ++r)
        #pragma unroll
        for (int c = 0; c < 4; ++c) acc[r][c] = 0.f;

    for (int kc = 0; kc < CD; kc += KC) {
        float4 a0 = *(const float4*)&X[(size_t)(bm * 64 + lr) * CD + kc + lq * 4];
        float4 a1 = *(const float4*)&X[(size_t)(bm * 64 + lr) * CD + kc + (lq + 4) * 4];
        float4 b0 = *(const float4*)&X[(size_t)(bn * 64 + lr) * CD + kc + lq * 4];
        float4 b1 = *(const float4*)&X[(size_t)(bn * 64 + lr) * CD + kc + (lq + 4) * 4];
        __syncthreads();
        As[lq * 4 + 0][lr] = a0.x; As[lq * 4 + 1][lr] = a0.y;
        As[lq * 4 + 2][lr] = a0.z; As[lq * 4 + 3][lr] = a0.w;
        As[lq * 4 + 16][lr] = a1.x; As[lq * 4 + 17][lr] = a1.y;
        As[lq * 4 + 18][lr] = a1.z; As[lq * 4 + 19][lr] = a1.w;
        Bs[lq * 4 + 0][lr] = b0.x; Bs[lq * 4 + 1][lr] = b0.y;
        Bs[lq * 4 + 2][lr] = b0.z; Bs[lq * 4 + 3][lr] = b0.w;
        Bs[lq * 4 + 16][lr] = b1.x; Bs[lq * 4 + 17][lr] = b1.y;
        Bs[lq * 4 + 18][lr] = b1.z; Bs[lq * 4 + 19][lr] = b1.w;
        __syncthreads();
        #pragma unroll
        for (int kk = 0; kk < KC; ++kk) {
            float4 av = *(const float4*)&As[kk][ty * 4];
            float4 bv = *(const float4*)&Bs[kk][tx * 4];
            acc[0][0] += av.x * bv.x; acc[0][1] += av.x * bv.y;
            acc[0][2] += av.x * bv.z; acc[0][3] += av.x * bv.w;
            acc[1][0] += av.y * bv.x; acc[1][1] += av.y * bv.y;
            acc[1][2] += av.y * bv.z; acc[1][3] += av.y * bv.w;
            acc[2][0] += av.z * bv.x; acc[2][1] += av.z * bv.y;
            acc[2][2] += av.z * bv.z; acc[2][3] += av.z * bv.w;
            acc[3][0] += av.w * bv.x; acc[3][1] += av.w * bv.y;
            acc[3][2] += av.w * bv.z; acc[3][3] += av.w * bv.w;
        }
    }
    size_t obase = (size_t)b * TN * TN;
    #pragma unroll
    for (int r = 0; r < 4; ++r) {
        int mrow = bm * 64 + ty * 4 + r;
        float4 o;
        o.x = 1.0f - acc[r][0]; o.y = 1.0f - acc[r][1];
        o.z = 1.0f - acc[r][2]; o.w = 1.0f - acc[r][3];
        size_t idx = obase + (size_t)mrow * TN + bn * 64 + tx * 4;
        *(float4*)&dout[idx] = o;
    }
}

// ---------------- init: NN keys parity0 + state seed ----------------
__global__ __launch_bounds__(1024)
void init_kernel(const float* __restrict__ Dist, ull* __restrict__ rkg2,
                 float* __restrict__ szg2, int* __restrict__ gidg2,
                 ull* __restrict__ mkg, int* __restrict__ metag2) {
    int b = blockIdx.x >> 4;
    int w = blockIdx.x & 15;
    int k = threadIdx.x;
    int lane = k & 63, wv = k >> 6;
    int gw = w * 16 + wv;
    const float* D0 = Dist + (size_t)b * TN * TN;
    for (int r = gw; r < TN; r += 256) {
        const float* Rr = D0 + (size_t)r * TN;
        ull best = ~0ull;
        for (int s = lane; s < TN; s += 64)
            if (s != r) {
                ull key = ((ull)f2sort(Rr[s]) << 32) | (uint32_t)s;
                if (key < best) best = key;
            }
        best = wmin64_all(best);
        if (lane == 0) rkg2[(size_t)b * TN + r] = best;
    }
    if (w == 0) {
        szg2[b * TN + k] = 1.0f;
        gidg2[b * TN + k] = k;
        mkg[(size_t)b * TN + k] = ~0ull;
        if (k == 0) {
            metag2[b * 4 + 0] = TN;   // N
            metag2[b * 4 + 1] = 0;    // nmerged
            metag2[b * 4 + 2] = 0;    // which: 0=Dinit 1=DA 2=DB
        }
    }
}

// ---------------- one head round: 16 WGs/batch, parity-buffered state ----------------
__global__ __launch_bounds__(1024)
void round_kernel(int round, const float* __restrict__ Dinit,
                  float* __restrict__ DA, float* __restrict__ DB,
                  ull* __restrict__ rkg2, float* __restrict__ szg2,
                  int* __restrict__ gidg2, ull* __restrict__ mkg,
                  int* __restrict__ metag2) {
    int wg = blockIdx.x;
    int b = wg % NB;
    int w = wg / NB;
    int k = threadIdx.x;
    int lane = k & 63, wv = k >> 6;
    int gw = w * 16 + wv;
    int par = round & 1;

    const int* meta = metag2 + par * NB * 4 + b * 4;
    int N = meta[0], nm = meta[1], which = meta[2];

    if (N <= TAILN) {                 // no-op round: copy state forward (w0 only)
        if (w == 0) {
            if (k < N) {
                szg2[(par ^ 1) * NB * TN + b * TN + k] = szg2[par * NB * TN + b * TN + k];
                gidg2[(par ^ 1) * NB * TN + b * TN + k] = gidg2[par * NB * TN + b * TN + k];
            }
            if (k == 0) {
                int* m2 = metag2 + (par ^ 1) * NB * 4 + b * 4;
                m2[0] = N; m2[1] = nm; m2[2] = which;
            }
        }
        return;
    }

    __shared__ ull rk_s[TN];
    __shared__ float sz_s[TN];
    __shared__ int gid_s[TN];
    __shared__ int ts_s[TN];
    __shared__ int n2o_s[TN];
    __shared__ unsigned char dead_s[TN];
    __shared__ int pi_t[512], pj_t[512];
    __shared__ ull pk_t[512];
    __shared__ int spi_s[512], spj_s[512];
    __shared__ int wcnt[16], woffp[16];
    __shared__ int npair_s;

    if (k < N) {
        rk_s[k] = rkg2[(size_t)par * NB * TN + (size_t)b * TN + k];
        sz_s[k] = szg2[par * NB * TN + b * TN + k];
        gid_s[k] = gidg2[par * NB * TN + b * TN + k];
    }
    ts_s[k] = -1;
    dead_s[k] = 0;
    __syncthreads();

    // ---- plan (redundant per WG, deterministic) ----
    bool mut = false; int cpart = 0;
    if (k < N) {
        ull K = rk_s[k];
        int c = (int)(uint32_t)K;
        if ((int)(uint32_t)rk_s[c] == k && k < c) { mut = true; cpart = c; }
    }
    ull bm = __ballot(mut);
    int lanepre = __popcll(bm & (((ull)1 << lane) - 1ull));
    if (lane == 0) wcnt[wv] = __popcll(bm);
    __syncthreads();
    if (k == 0) {
        int run = 0;
        #pragma unroll
        for (int u = 0; u < 16; ++u) { woffp[u] = run; run += wcnt[u]; }
        npair_s = run;
    }
    __syncthreads();
    if (mut) { int idx = woffp[wv] + lanepre; pi_t[idx] = k; pj_t[idx] = cpart; }
    __syncthreads();
    int np = npair_s;
    if (np == 0) {                     // defensive: force global-min pair
        ull cand = ~0ull;
        if (k < N) cand = (rk_s[k] & HIMASK) | (uint32_t)k;
        cand = wmin64_all(cand);
        if (lane == 0) pk_t[wv] = cand;
        __syncthreads();
        if (k == 0) {
            ull g = pk_t[0];
            for (int u = 1; u < 16; ++u) if (pk_t[u] < g) g = pk_t[u];
            int r = (int)(uint32_t)g;
            int c = (int)(uint32_t)rk_s[r];
            pi_t[0] = r < c ? r : c;
            pj_t[0] = r < c ? c : r;
            npair_s = 1;
        }
        __syncthreads();
        np = 1;
    }
    if (k < np) {
        int i = pi_t[k], j = pj_t[k];
        uint32_t vb = (uint32_t)(rk_s[i] >> 32);
        pk_t[k] = ((ull)vb << 20) | ((ull)(uint32_t)gid_s[i] << 10) | (ull)(uint32_t)gid_s[j];
    }
    __syncthreads();
    if (k < np) {                      // rank-sort (keys distinct: gid_j unique)
        ull mk = pk_t[k];
        int rank = 0;
        for (int u = 0; u < np; ++u) if (pk_t[u] < mk) ++rank;
        spi_s[rank] = pi_t[k]; spj_s[rank] = pj_t[k];
        if (w == 0) mkg[(size_t)b * TN + nm + rank] = mk;   // merge record
    }
    __syncthreads();
    if (k < np) { ts_s[spi_s[k]] = k; dead_s[spj_s[k]] = 1; }
    __syncthreads();
    bool alive_ = (k < N) && !dead_s[k];
    ull am = __ballot(alive_);
    int apre = __popcll(am & (((ull)1 << lane) - 1ull));
    if (lane == 0) wcnt[wv] = __popcll(am);
    __syncthreads();
    if (k == 0) {
        int run = 0;
        #pragma unroll
        for (int u = 0; u < 16; ++u) { woffp[u] = run; run += wcnt[u]; }
    }
    __syncthreads();
    if (alive_) n2o_s[woffp[wv] + apre] = k;
    int Nn = N - np;
    __syncthreads();

    // ---- rewrite cur(N) -> nxt(Nn), fused NN -> rkg2[par^1] ----
    const float* cur = (which == 0) ? (Dinit + (size_t)b * TN * TN)
                      : ((which == 1) ? DA : DB) + (size_t)b * TN * TN;
    float* nxt = ((which == 1) ? DB : DA) + (size_t)b * TN * TN;
    int newwhich = (which == 1) ? 2 : 1;

    for (int ap = gw; ap < Nn; ap += 256) {
        int a = n2o_s[ap];
        int qa = ts_s[a];
        float* drow = nxt + (size_t)ap * Nn;
        ull best = ~0ull;
        if (qa < 0) {
            const float* Ra = cur + (size_t)a * N;
            for (int bp = lane; bp < Nn; bp += 64) {
                int bo = n2o_s[bp];
                int qb = ts_s[bo];
                float val;
                if (qb < 0) val = Ra[bo];
                else {
                    int iq = spi_s[qb], jq = spj_s[qb];
                    float niq = sz_s[iq], njq = sz_s[jq];
                    float sq = __fadd_rn(niq, njq);
                    val = __fdiv_rn(__fadd_rn(__fmul_rn(niq, Ra[iq]),
                                              __fmul_rn(njq, Ra[jq])), sq);
                }
                drow[bp] = val;
                if (bp != ap) {
                    ull key = ((ull)f2sort(val) << 32) | (uint32_t)bp;
                    if (key < best) best = key;
                }
            }
        } else {
            int ii = spi_s[qa], jj = spj_s[qa];
            float ni = sz_s[ii], nj = sz_s[jj], ss = __fadd_rn(ni, nj);
            const float* Ri = cur + (size_t)ii * N;
            const float* Rj = cur + (size_t)jj * N;
            for (int bp = lane; bp < Nn; bp += 64) {
                int bo = n2o_s[bp];
                int qb = ts_s[bo];
                float val;
                if (qb < 0) {
                    val = __fdiv_rn(__fadd_rn(__fmul_rn(ni, Ri[bo]),
                                              __fmul_rn(nj, Rj[bo])), ss);
                } else if (qb == qa) {
                    val = 0.0f;        // diagonal, never read
                } else {
                    int p = qa < qb ? qa : qb, q2 = qa < qb ? qb : qa;
                    int ip = spi_s[p], jp = spj_s[p], iq = spi_s[q2], jq = spj_s[q2];
                    float nip = sz_s[ip], njp = sz_s[jp], sp = __fadd_rn(nip, njp);
                    float niq = sz_s[iq], njq = sz_s[jq], sq = __fadd_rn(niq, njq);
                    float t1 = __fdiv_rn(__fadd_rn(__fmul_rn(nip, cur[(size_t)ip * N + iq]),
                                                   __fmul_rn(njp, cur[(size_t)jp * N + iq])), sp);
                    float t2 = __fdiv_rn(__fadd_rn(__fmul_rn(nip, cur[(size_t)ip * N + jq]),
                                                   __fmul_rn(njp, cur[(size_t)jp * N + jq])), sp);
                    val = __fdiv_rn(__fadd_rn(__fmul_rn(niq, t1), __fmul_rn(njq, t2)), sq);
                }
                drow[bp] = val;
                if (bp != ap) {
                    ull key = ((ull)f2sort(val) << 32) | (uint32_t)bp;
                    if (key < best) best = key;
                }
            }
        }
        best = wmin64_all(best);
        if (lane == 0) rkg2[(size_t)(par ^ 1) * NB * TN + (size_t)b * TN + ap] = best;
    }

    // ---- compacted sizes/gid + meta -> parity^1 (w0 only) ----
    if (w == 0) {
        if (k < Nn) {
            int a = n2o_s[k]; int q = ts_s[a];
            float ns = (q >= 0) ? __fadd_rn(sz_s[spi_s[q]], sz_s[spj_s[q]]) : sz_s[a];
            szg2[(par ^ 1) * NB * TN + b * TN + k] = ns;
            gidg2[(par ^ 1) * NB * TN + b * TN + k] = gid_s[a];
        }
        if (k == 0) {
            int* m2 = metag2 + (par ^ 1) * NB * 4 + b * 4;
            m2[0] = Nn; m2[1] = nm + np; m2[2] = newwhich;
        }
    }
}

// ---------------- tail: LDS-resident finish + cut + labels (verbatim R14) ----------------
__global__ __launch_bounds__(1024)
void tail_kernel(int fpar, const float* __restrict__ DA, const float* __restrict__ DB,
                 const float* __restrict__ szg2, const int* __restrict__ gidg2,
                 const ull* __restrict__ mkg, const int* __restrict__ metag2,
                 float* __restrict__ out_labels) {
    int b = blockIdx.x;
    int k = threadIdx.x;
    int lane = k & 63, wv = k >> 6;

    __shared__ float Dl[TAILN * TAILN];
    __shared__ ull rk_s[TAILN];
    __shared__ float sz_s[TAILN];
    __shared__ int gid_s[TAILN];
    __shared__ unsigned char alive[TAILN];
    __shared__ int tsl[TAILN];
    __shared__ float F[PCAP * PCAP];
    __shared__ int pi_t[96], pj_t[96];
    __shared__ ull pk_t[96];
    __shared__ int spi_s[PCAP], spj_s[PCAP];
    __shared__ ull mk_s[TN];
    __shared__ int par_s[TN];
    __shared__ uint32_t rw[32];
    __shared__ int woff2[32];
    __shared__ ull wpA[16];
    __shared__ int npair_s;

    int N = metag2[fpar * NB * 4 + b * 4 + 0];
    int nm = metag2[fpar * NB * 4 + b * 4 + 1];
    int which = metag2[fpar * NB * 4 + b * 4 + 2];
    const float* src = ((which == 1) ? DA : DB) + (size_t)b * TN * TN;

    for (int idx = k; idx < N * N; idx += 1024) Dl[idx] = src[idx];
    mk_s[k] = mkg[(size_t)b * TN + k];
    if (k < N) {
        sz_s[k] = szg2[fpar * NB * TN + b * TN + k];
        gid_s[k] = gidg2[fpar * NB * TN + b * TN + k];
        alive[k] = 1;
        tsl[k] = -1;
    }
    __syncthreads();

    int na = N;
    for (int round = 0; round < 600 && na > 1; ++round) {
        for (int r = wv; r < N; r += 16) {
            ull best = ~0ull;
            if (alive[r]) {
                for (int s = lane; s < N; s += 64)
                    if (alive[s] && s != r) {
                        ull key = ((ull)f2sort(Dl[r * N + s]) << 32) | (uint32_t)s;
                        if (key < best) best = key;
                    }
                best = wmin64_all(best);
            }
            if (lane == 0) rk_s[r] = best;
        }
        if (k == 0) npair_s = 0;
        __syncthreads();
        if (k < N && alive[k]) {
            ull K = rk_s[k];
            int c = (int)(uint32_t)K;
            if ((int)(uint32_t)rk_s[c] == k && k < c) {
                int idx = atomicAdd(&npair_s, 1);
                pi_t[idx] = k; pj_t[idx] = c;
            }
        }
        __syncthreads();
        int np = npair_s;
        if (np == 0) {
            ull cand = ~0ull;
            if (k < N && alive[k]) cand = (rk_s[k] & HIMASK) | (uint32_t)k;
            cand = wmin64_all(cand);
            if (lane == 0) wpA[wv] = cand;
            __syncthreads();
            if (k == 0) {
                ull g = wpA[0];
                for (int u = 1; u < 16; ++u) if (wpA[u] < g) g = wpA[u];
                int r = (int)(uint32_t)g;
                int c = (int)(uint32_t)rk_s[r];
                pi_t[0] = r < c ? r : c;
                pj_t[0] = r < c ? c : r;
                npair_s = 1;
            }
            __syncthreads();
            np = 1;
        }
        int P = np < PCAP ? np : PCAP;
        if (k < np) {
            int i = pi_t[k], j = pj_t[k];
            uint32_t vb = (uint32_t)(rk_s[i] >> 32);
            pk_t[k] = ((ull)vb << 20) | ((ull)(uint32_t)gid_s[i] << 10) | (ull)(uint32_t)gid_s[j];
        }
        __syncthreads();
        if (k < np) {
            ull mk = pk_t[k];
            int rank = 0;
            for (int u = 0; u < np; ++u) if (pk_t[u] < mk) ++rank;
            if (rank < P) { spi_s[rank] = pi_t[k]; spj_s[rank] = pj_t[k]; mk_s[nm + rank] = mk; }
        }
        __syncthreads();
        for (int t = k; t < P * P; t += 1024) {
            int p = t / P, q = t - p * P;
            if (p < q) {
                int ip = spi_s[p], jp = spj_s[p], iq = spi_s[q], jq = spj_s[q];
                float nip = sz_s[ip], njp = sz_s[jp], sp = __fadd_rn(nip, njp);
                float niq = sz_s[iq], njq = sz_s[jq], sq = __fadd_rn(niq, njq);
                float t1 = __fdiv_rn(__fadd_rn(__fmul_rn(nip, Dl[ip * N + iq]),
                                               __fmul_rn(njp, Dl[jp * N + iq])), sp);
                float t2 = __fdiv_rn(__fadd_rn(__fmul_rn(nip, Dl[ip * N + jq]),
                                               __fmul_rn(njp, Dl[jp * N + jq])), sp);
                F[p * PCAP + q] = __fdiv_rn(__fadd_rn(__fmul_rn(niq, t1), __fmul_rn(njq, t2)), sq);
            }
        }
        if (k < P) { tsl[spi_s[k]] = k; alive[spj_s[k]] = 0; }
        __syncthreads();
        for (int q = wv; q < P; q += 16) {
            int ii = spi_s[q], jj = spj_s[q];
            float ni = sz_s[ii], nj = sz_s[jj], ss = __fadd_rn(ni, nj);
            for (int s = lane; s < N; s += 64) {
                if (!alive[s] || s == ii) continue;
                int tp = tsl[s];
                float val;
                if (tp >= 0) {
                    int p2 = tp < q ? tp : q, q2 = tp < q ? q : tp;
                    val = F[p2 * PCAP + q2];
                } else {
                    val = __fdiv_rn(__fadd_rn(__fmul_rn(ni, Dl[ii * N + s]),
                                              __fmul_rn(nj, Dl[jj * N + s])), ss);
                }
                Dl[ii * N + s] = val;
                Dl[s * N + ii] = val;
            }
        }
        __syncthreads();
        if (k < P) {
            int ii = spi_s[k];
            sz_s[ii] = __fadd_rn(sz_s[ii], sz_s[spj_s[k]]);
            tsl[ii] = -1;
        }
        nm += P;
        na -= P;
        __syncthreads();
    }

    // epilogue: cut at 828 smallest merge keys, union-find, rank labels
    __syncthreads();
    par_s[k] = k;
    if (k < 32) rw[k] = 0;
    __syncthreads();
    if (k < TN - 1) {
        ull mk = mk_s[k];
        if (mk != ~0ull) {
            int rank = 0;
            for (int u = 0; u < TN - 1; ++u) if (mk_s[u] < mk) ++rank;
            if (rank < NMERGE) {
                int jj = (int)(mk & 1023ull);
                int ii = (int)((mk >> 10) & 1023ull);
                par_s[jj] = ii;
            }
        }
    }
    __syncthreads();
    #pragma unroll
    for (int it = 0; it < 11; ++it) {
        int p1 = par_s[k];
        int g = par_s[p1];
        __syncthreads();
        par_s[k] = g;
        __syncthreads();
    }
    if (par_s[k] == k) atomicOr(&rw[k >> 5], 1u << (k & 31));
    __syncthreads();
    if (k == 0) {
        int run = 0;
        for (int u = 0; u < 32; ++u) { woff2[u] = run; run += __popc(rw[u]); }
    }
    __syncthreads();
    int p = par_s[k];
    int rank = woff2[p >> 5] + __popc(rw[p >> 5] & ((1u << (p & 31)) - 1u));
    out_labels[(size_t)b * TN + k] = (float)rank;
}

extern "C" void kernel_launch(void* const* d_in, const int* in_sizes, int n_in,
                              void* d_out, int out_size, void* d_ws, size_t ws_size,
                              hipStream_t stream) {
    const float* x = (const float*)d_in[0];
    float* out = (float*)d_out;

    float* xn    = (float*)d_ws;                            // NB*TN*CD  (6.29 MB)
    float* DAp   = xn + (size_t)NB * TN * CD;               // NB*TN*TN  (33.6 MB)
    float* DBp   = DAp + (size_t)NB * TN * TN;              // NB*TN*TN  (33.6 MB)
    ull*   rkg2  = (ull*)(DBp + (size_t)NB * TN * TN);      // 2*NB*TN u64 (128 KB)
    float* szg2  = (float*)(rkg2 + 2 * (size_t)NB * TN);    // 2*NB*TN f32
    int*   gidg2 = (int*)(szg2 + 2 * (size_t)NB * TN);      // 2*NB*TN i32
    ull*   mkg   = (ull*)(gidg2 + 2 * (size_t)NB * TN);     // NB*TN u64
    int*   metag2 = (int*)(mkg + (size_t)NB * TN);          // 2*NB*4 ints

    float* dist_out   = out;
    float* labels_out = out + (size_t)NB * TN * TN;

    norm_kernel<<<NB * TN, 256, 0, stream>>>(x, xn);
    dim3 g2(16, 16, NB);
    dist_kernel<<<g2, 256, 0, stream>>>(xn, dist_out);
    init_kernel<<<NWG, 1024, 0, stream>>>(dist_out, rkg2, szg2, gidg2, mkg, metag2);
    for (int r = 0; r < NROUNDS; ++r)
        round_kernel<<<NWG, 1024, 0, stream>>>(r, dist_out, DAp, DBp,
                                               rkg2, szg2, gidg2, mkg, metag2);
    tail_kernel<<<NB, 1024, 0, stream>>>(NROUNDS & 1, DAp, DBp, szg2, gidg2,
                                         mkg, metag2, labels_out);
}